// Round 3
// baseline (1548.026 us; speedup 1.0000x reference)
//
#include <hip/hip_runtime.h>
#include <hip/hip_bf16.h>

// EarthAttention2D on MI355X (gfx950).
// B_WIN=2048, N=128, DIM=512, HEADS=16, hd=32, M = 2048*128 = 262144.
// Pipeline: cvt_x (x->bf16) + prep (weights->bf16, epb gather)
//        -> QKV GEMM (256^2 8-phase, counted vmcnt, setprio, bf16 MFMA)
//        -> fused window attention
//        -> proj GEMM (same template, f32 out).

typedef short short8 __attribute__((ext_vector_type(8)));
typedef float f32x4 __attribute__((ext_vector_type(4)));
typedef unsigned short u16;
typedef unsigned int u32;

__device__ __forceinline__ u16 f2bf(float f) {
    __bf16 h = (__bf16)f;                    // RNE fptrunc -> v_cvt on gfx950
    union { __bf16 b; u16 u; } v; v.b = h;
    return v.u;
}

__device__ __forceinline__ f32x4 mfma16(short8 a, short8 b, f32x4 c) {
    return __builtin_amdgcn_mfma_f32_16x16x32_bf16(a, b, c, 0, 0, 0);
}

// async global->LDS, 16B per lane, dest = wave-uniform base + lane*16
#define GLDS16(gsrc, ldst)                                                  \
    __builtin_amdgcn_global_load_lds(                                       \
        (const __attribute__((address_space(1))) void*)(gsrc),              \
        (__attribute__((address_space(3))) void*)(ldst), 16, 0, 0)

// ---------------------------------------------------------------- cvt_x ----
__global__ __launch_bounds__(256) void cvt_x_kernel(
    const float4* __restrict__ xin, int4* __restrict__ xbf)
{
    int idx = blockIdx.x * 256 + threadIdx.x;           // unit = 8 floats
    for (; idx < 16777216; idx += 8192 * 256) {
        const float4 a = xin[idx * 2], b = xin[idx * 2 + 1];
        int4 o;
        o.x = (u32)f2bf(a.x) | ((u32)f2bf(a.y) << 16);
        o.y = (u32)f2bf(a.z) | ((u32)f2bf(a.w) << 16);
        o.z = (u32)f2bf(b.x) | ((u32)f2bf(b.y) << 16);
        o.w = (u32)f2bf(b.z) | ((u32)f2bf(b.w) << 16);
        xbf[idx] = o;
    }
}

// ---------------------------------------------------------------- prep ----
__global__ __launch_bounds__(256) void prep_kernel(
    const float* __restrict__ qkv_w, const float* __restrict__ proj_w,
    const float* __restrict__ btab, const int* __restrict__ pidx,
    u16* __restrict__ qkvw_bf, u16* __restrict__ projw_bf,
    float* __restrict__ epb)
{
    const int i = blockIdx.x * 256 + threadIdx.x;    // grid = 3072*256 = 786432
    qkvw_bf[i] = f2bf(qkv_w[i]);
    if (i < 512 * 512) projw_bf[i] = f2bf(proj_w[i]);
    if (i < 16 * 128 * 128) {
        const int rc = i & 16383, h = i >> 14;
        epb[i] = btab[pidx[rc] * 128 + 64 + h];      // bias_table[idx][TOW/2=4][h]
    }
}

// ---------------------------------------------------------------- GEMM ----
// 256x256 tile, BK=64, 512 threads (8 waves, 2M x 4N), per-wave 128x64 out.
// LDS 128 KiB: A[2][256][64] bf16 + B[2][256][64] bf16 (dbuf by tile parity).
// Content swizzle: 16B slot sl of row r holds global col-block (sl ^ (r&7)).
// 8 phases / 2 K-tiles; per phase: ds_reads + 1 half-tile stage + barrier +
// lgkmcnt(0) + 16 MFMA + barrier; vmcnt(2) only at phases 4/8 (vmcnt(0) at
// tail when prefetch predicated off).
//
// Overwrite-safety ledger (iteration i, tiles t=2i,t+1; buf = tile&1):
//   P1 stages (t+1).A1 over (t-1).A1  [last read P7(i-1), 2+ barriers ago]
//   P2 stages (t+1).B0 over (t-1).B0  [last read P8(i-1)]
//   P3 stages (t+1).B1 over (t-1).B1  [last read P8(i-1)]
//   P4 stages (t+2).A0 over  t   .A0  [last read P3(i)] + vmcnt
//   P5 stages (t+2).A1 over  t   .A1  [last read P3(i)]
//   P6 stages (t+2).B0 over  t   .B0  [last read P4(i)]
//   P7 stages (t+2).B1 over  t   .B1  [last read P4(i)]
//   P8 stages (t+3).A0 over (t+1).A0  [last read P7(i)] + vmcnt
// vmcnt(2) at P4: pending = P4's own 2 loads -> tile t+1 fully resident
// before P5 reads it.  Symmetric at P8 for tile t+2 before P1(i+1).

template<int BUF, int KS, int NH, int SX, int SHI, int SBUF, bool DOVM>
__device__ __forceinline__ void gemm_phase(
    char* sm, int aOff, int bOff, int colA,
    short8 (&aF)[8], f32x4 (&acc)[8][4],
    const u16* pX0, const u16* pX1, int wu1024, int st, int nk)
{
    short8 bF[2];
    if constexpr (NH == 0) {
#pragma unroll
        for (int mi = 0; mi < 8; ++mi)
            aF[mi] = *(const short8*)(sm + BUF * 32768 + aOff + mi * 2048 + colA);
    }
#pragma unroll
    for (int j = 0; j < 2; ++j)
        bF[j] = *(const short8*)(sm + 65536 + BUF * 32768 + bOff
                                 + (NH * 2 + j) * 2048 + colA);
    if (st < nk) {
        char* d = sm + SX * 65536 + SBUF * 32768 + SHI * 16384 + wu1024;
        const int koff = st << 6;
        GLDS16(pX0 + koff, d);
        GLDS16(pX1 + koff, d + 8192);
    }
    asm volatile("" ::: "memory");
    __builtin_amdgcn_s_barrier();
    asm volatile("s_waitcnt lgkmcnt(0)" ::: "memory");
    __builtin_amdgcn_sched_barrier(0);
    __builtin_amdgcn_s_setprio(1);
#pragma unroll
    for (int mi = 0; mi < 8; ++mi)
#pragma unroll
        for (int j = 0; j < 2; ++j)
            acc[mi][NH * 2 + j] = mfma16(aF[mi], bF[j], acc[mi][NH * 2 + j]);
    __builtin_amdgcn_s_setprio(0);
    __builtin_amdgcn_sched_barrier(0);
    if constexpr (DOVM) {
        if (st < nk) asm volatile("s_waitcnt vmcnt(2)" ::: "memory");
        else         asm volatile("s_waitcnt vmcnt(0)" ::: "memory");
    }
    asm volatile("" ::: "memory");
    __builtin_amdgcn_s_barrier();
}

template<bool EPI_QKV>
__global__ __launch_bounds__(512, 2) void gemm_bt(
    const u16* __restrict__ A, const u16* __restrict__ Bt,
    const float* __restrict__ bias, void* __restrict__ Cv,
    const int Nn, const int K, const float qscale)
{
    __shared__ __attribute__((aligned(128))) char sm[131072];

    const int tid = threadIdx.x;
    const int lane = tid & 63;
    const int w = tid >> 6;                              // 0..7
    const int lo = lane & 15, g = lane >> 4;
    const int wm = w >> 2, wn = w & 3;                   // 2M x 4N
    const int wu1024 = __builtin_amdgcn_readfirstlane(w) * 1024;
    const int ntile = Nn >> 8;

    int wg = blockIdx.x;
    {   // bijective XCD swizzle (gridDim % 8 == 0 for all launches)
        const int cpx = gridDim.x >> 3;
        wg = (wg & 7) * cpx + (wg >> 3);
    }
    const int bm = wg / ntile, bn = wg % ntile;
    const size_t m0 = (size_t)bm << 8;
    const int n0 = bn << 8;
    const int nk = K >> 6;                               // 8 here (even, >=4)

    // per-thread global source pointers (inverse content swizzle, m173)
    const u16* pA[2][2];
    const u16* pB[2][2];
#pragma unroll
    for (int round = 0; round < 2; ++round) {
        const int rl = (round * 512 + tid) >> 3;         // 0..127
        const int c16 = tid & 7;
        const int csw = (c16 ^ (rl & 7)) << 3;
#pragma unroll
        for (int hi = 0; hi < 2; ++hi) {
            pA[round][hi] = A + (m0 + hi * 128 + rl) * (size_t)K + csw;
            pB[round][hi] = Bt + (size_t)(n0 + hi * 128 + rl) * K + csw;
        }
    }

    // ds_read address components
    const int aOff  = (wm * 128 + lo) * 128;             // byte row base (A)
    const int bOff  = (wn * 64 + lo) * 128;              // byte row base (B)
    const int colA0 = ((0 * 4 + g) ^ (lo & 7)) << 4;     // k-slice 0
    const int colA1 = ((1 * 4 + g) ^ (lo & 7)) << 4;     // k-slice 1

    short8 aF[8];
    f32x4 acc[8][4] = {};

    // prologue: tile0 full + tile1.A0, then vmcnt(2) -> tile0 resident
    {
        char* dA = sm + wu1024;
        char* dB = sm + 65536 + wu1024;
        GLDS16(pA[0][0], dA);          GLDS16(pA[1][0], dA + 8192);
        GLDS16(pA[0][1], dA + 16384);  GLDS16(pA[1][1], dA + 24576);
        GLDS16(pB[0][0], dB);          GLDS16(pB[1][0], dB + 8192);
        GLDS16(pB[0][1], dB + 16384);  GLDS16(pB[1][1], dB + 24576);
        char* dA1 = sm + 32768 + wu1024;                 // tile1 (buf1) A0
        GLDS16(pA[0][0] + 64, dA1);    GLDS16(pA[1][0] + 64, dA1 + 8192);
        asm volatile("s_waitcnt vmcnt(2)" ::: "memory");
        asm volatile("" ::: "memory");
        __builtin_amdgcn_s_barrier();
    }

    for (int t = 0; t < nk; t += 2) {
        //            BUF KS NH  SX SHI SBUF VM
        gemm_phase<0, 0, 0, 0, 1, 1, false>(sm, aOff, bOff, colA0, aF, acc,
            pA[0][1], pA[1][1], wu1024, t + 1, nk);      // P1: (t+1).A1
        gemm_phase<0, 0, 1, 1, 0, 1, false>(sm, aOff, bOff, colA0, aF, acc,
            pB[0][0], pB[1][0], wu1024, t + 1, nk);      // P2: (t+1).B0
        gemm_phase<0, 1, 0, 1, 1, 1, false>(sm, aOff, bOff, colA1, aF, acc,
            pB[0][1], pB[1][1], wu1024, t + 1, nk);      // P3: (t+1).B1
        gemm_phase<0, 1, 1, 0, 0, 0, true >(sm, aOff, bOff, colA1, aF, acc,
            pA[0][0], pA[1][0], wu1024, t + 2, nk);      // P4: (t+2).A0 +vm
        gemm_phase<1, 0, 0, 0, 1, 0, false>(sm, aOff, bOff, colA0, aF, acc,
            pA[0][1], pA[1][1], wu1024, t + 2, nk);      // P5: (t+2).A1
        gemm_phase<1, 0, 1, 1, 0, 0, false>(sm, aOff, bOff, colA0, aF, acc,
            pB[0][0], pB[1][0], wu1024, t + 2, nk);      // P6: (t+2).B0
        gemm_phase<1, 1, 0, 1, 1, 0, false>(sm, aOff, bOff, colA1, aF, acc,
            pB[0][1], pB[1][1], wu1024, t + 2, nk);      // P7: (t+2).B1
        gemm_phase<1, 1, 1, 0, 0, 1, true >(sm, aOff, bOff, colA1, aF, acc,
            pA[0][0], pA[1][0], wu1024, t + 3, nk);      // P8: (t+3).A0 +vm
    }

    if constexpr (EPI_QKV) {
        // restage C (256x256 bf16) through LDS in 2 rounds of 128 rows,
        // stride 264 u16 (16B-aligned rows, conflict-reduced).
        u16* Ct = (u16*)sm;
        u16* Cg = (u16*)Cv;
#pragma unroll
        for (int p = 0; p < 2; ++p) {
            __syncthreads();
            if (wm == p) {
#pragma unroll
                for (int nj = 0; nj < 4; ++nj) {
                    const int c = wn * 64 + nj * 16 + lo;
                    const float bv = bias[n0 + c];
                    const float sc = (n0 + c < 512) ? qscale : 1.0f;
#pragma unroll
                    for (int mi = 0; mi < 8; ++mi)
#pragma unroll
                        for (int ii = 0; ii < 4; ++ii) {
                            const int r = mi * 16 + g * 4 + ii;
                            Ct[r * 264 + c] = f2bf((acc[mi][nj][ii] + bv) * sc);
                        }
                }
            }
            __syncthreads();
#pragma unroll
            for (int it = 0; it < 8; ++it) {
                const int idx = it * 512 + tid;
                const int r = idx >> 5, seg = idx & 31;
                *(int4*)(Cg + (m0 + p * 128 + r) * (size_t)Nn + n0 + seg * 8) =
                    *(const int4*)(Ct + r * 264 + seg * 8);
            }
        }
    } else {
        float* Cg = (float*)Cv;
#pragma unroll
        for (int nj = 0; nj < 4; ++nj) {
            const int c = wn * 64 + nj * 16 + lo;
            const float bv = bias[n0 + c];
#pragma unroll
            for (int mi = 0; mi < 8; ++mi)
#pragma unroll
                for (int ii = 0; ii < 4; ++ii) {
                    const size_t r = m0 + wm * 128 + mi * 16 + g * 4 + ii;
                    Cg[r * (size_t)Nn + n0 + c] = acc[mi][nj][ii] + bv;
                }
        }
    }
}

// ----------------------------------------------------------- attention ----
// One block (4 waves) per (b, h). qkv layout: [b*128+n][t*512 + h*32 + d].
// Union LDS (42.5 KiB -> 3 blocks/CU): Ps overlaps Qs/Ks, Os overlaps Vt.
__global__ __launch_bounds__(256) void attn_kernel(
    const u16* __restrict__ qkv, const float* __restrict__ epb,
    u16* __restrict__ aout)
{
    __shared__ __attribute__((aligned(16))) char smem[43520];
    u16 (*Vt)[136]      = (u16(*)[136])smem;                 // [32][136]
    u16 (*Qs)[32]       = (u16(*)[32])(smem + 8704);         // [128][32]
    u16 (*Ks)[32]       = (u16(*)[32])(smem + 16896);        // [128][32]
    u16 (*Ps)[32][136]  = (u16(*)[32][136])(smem + 8704);    // [4][32][136]
    u16 (*Os)[32]       = (u16(*)[32])smem;                  // [128][32]

    const int h = blockIdx.x >> 11;
    const int b = blockIdx.x & 2047;
    const int tid = threadIdx.x;
    const int lane = tid & 63, w = tid >> 6;
    const int lo = lane & 15, g = lane >> 4;

    const size_t base = (size_t)b * 128 * 1536 + h * 32;
#pragma unroll
    for (int it = 0; it < 2; ++it) {
        const int s = tid + it * 256;            // 0..511
        const int n = s >> 2, c = (s & 3) * 8;
        const u16* p = qkv + base + (size_t)n * 1536 + c;
        *(int4*)(&Qs[n][c]) = *(const int4*)(p);
        *(int4*)(&Ks[n][c]) = *(const int4*)(p + 512);
        union { int4 q; u16 u[8]; } vu;
        vu.q = *(const int4*)(p + 1024);
#pragma unroll
        for (int j = 0; j < 8; ++j) Vt[c + j][n] = vu.u[j];
    }
    __syncthreads();

    const int r0 = w * 32;

    // ---- S = Q @ K^T ----
    short8 aq[2], bk[8];
    aq[0] = *(const short8*)(&Qs[r0 + lo][g * 8]);
    aq[1] = *(const short8*)(&Qs[r0 + 16 + lo][g * 8]);
#pragma unroll
    for (int j = 0; j < 8; ++j) bk[j] = *(const short8*)(&Ks[j * 16 + lo][g * 8]);

    f32x4 acc[2][8];
#pragma unroll
    for (int j = 0; j < 8; ++j) {
        f32x4 z = {0.f, 0.f, 0.f, 0.f};
        acc[0][j] = mfma16(aq[0], bk[j], z);
        acc[1][j] = mfma16(aq[1], bk[j], z);
    }

    // ---- bias + row max ----
    const float* eb = epb + (h << 14);
    float mrow[2][4], rsum[2][4];
#pragma unroll
    for (int mt = 0; mt < 2; ++mt)
#pragma unroll
        for (int ii = 0; ii < 4; ++ii) { mrow[mt][ii] = -1e30f; rsum[mt][ii] = 0.f; }

#pragma unroll
    for (int mt = 0; mt < 2; ++mt)
#pragma unroll
        for (int j = 0; j < 8; ++j)
#pragma unroll
            for (int ii = 0; ii < 4; ++ii) {
                const int r = r0 + mt * 16 + g * 4 + ii;
                const int c = j * 16 + lo;
                const float sv = acc[mt][j][ii] + eb[(r << 7) + c];
                acc[mt][j][ii] = sv;
                mrow[mt][ii] = fmaxf(mrow[mt][ii], sv);
            }
#pragma unroll
    for (int d = 1; d < 16; d <<= 1)
#pragma unroll
        for (int mt = 0; mt < 2; ++mt)
#pragma unroll
            for (int ii = 0; ii < 4; ++ii)
                mrow[mt][ii] = fmaxf(mrow[mt][ii], __shfl_xor(mrow[mt][ii], d, 64));

    __syncthreads();   // all waves done reading Qs/Ks -> Ps may overwrite

    // ---- exp -> Ps (per-wave private region), row sums ----
#pragma unroll
    for (int mt = 0; mt < 2; ++mt)
#pragma unroll
        for (int j = 0; j < 8; ++j)
#pragma unroll
            for (int ii = 0; ii < 4; ++ii) {
                const float p = __expf(acc[mt][j][ii] - mrow[mt][ii]);
                rsum[mt][ii] += p;
                Ps[w][mt * 16 + g * 4 + ii][j * 16 + lo] = f2bf(p);
            }
#pragma unroll
    for (int d = 1; d < 16; d <<= 1)
#pragma unroll
        for (int mt = 0; mt < 2; ++mt)
#pragma unroll
            for (int ii = 0; ii < 4; ++ii)
                rsum[mt][ii] += __shfl_xor(rsum[mt][ii], d, 64);

    // ---- O = P @ V ----
    f32x4 o[2][2] = {};
#pragma unroll
    for (int kk = 0; kk < 4; ++kk) {
        short8 av[2];
        av[0] = *(const short8*)(&Ps[w][lo][kk * 32 + g * 8]);
        av[1] = *(const short8*)(&Ps[w][16 + lo][kk * 32 + g * 8]);
#pragma unroll
        for (int dt = 0; dt < 2; ++dt) {
            const short8 bv = *(const short8*)(&Vt[dt * 16 + lo][kk * 32 + g * 8]);
            o[0][dt] = mfma16(av[0], bv, o[0][dt]);
            o[1][dt] = mfma16(av[1], bv, o[1][dt]);
        }
    }

    __syncthreads();   // all waves done reading Vt -> Os may overwrite

    // ---- normalize -> Os, coalesced int4 stores ----
#pragma unroll
    for (int mt = 0; mt < 2; ++mt)
#pragma unroll
        for (int dt = 0; dt < 2; ++dt)
#pragma unroll
            for (int ii = 0; ii < 4; ++ii)
                Os[r0 + mt * 16 + g * 4 + ii][dt * 16 + lo] =
                    f2bf(o[mt][dt][ii] / rsum[mt][ii]);
    __syncthreads();

    u16* op = aout + (size_t)b * 128 * 512 + h * 32;
#pragma unroll
    for (int it = 0; it < 2; ++it) {
        const int idx = tid + it * 256;          // 0..511
        const int r = idx >> 2, c = (idx & 3) * 8;
        *(int4*)(op + (size_t)r * 512 + c) = *(const int4*)(&Os[r][c]);
    }
}

// -------------------------------------------------------------- launch ----
extern "C" void kernel_launch(void* const* d_in, const int* in_sizes, int n_in,
                              void* d_out, int out_size, void* d_ws, size_t ws_size,
                              hipStream_t stream)
{
    const float* x      = (const float*)d_in[0];
    const float* qkv_w  = (const float*)d_in[1];
    const float* qkv_b  = (const float*)d_in[2];
    const float* proj_w = (const float*)d_in[3];
    const float* proj_b = (const float*)d_in[4];
    const float* btab   = (const float*)d_in[5];
    const int*   pidx   = (const int*)d_in[6];

    // workspace layout (bytes), total 1,076,887,552
    // xbf aliases attnbuf: x_bf16 is dead before attn writes its output.
    char* ws = (char*)d_ws;
    u16*   xbf      = (u16*)(ws);                        // 268,435,456
    u16*   attnbuf  = (u16*)(ws);                        // (alias)
    u16*   qkvw_bf  = (u16*)(ws + 268435456);            //   1,572,864
    u16*   projw_bf = (u16*)(ws + 270008320);            //     524,288
    float* epb      = (float*)(ws + 270532608);          //   1,048,576
    u16*   qkvbuf   = (u16*)(ws + 271581184);            // 805,306,368

    const float qscale = 0.17677669529663687f;           // 32^-0.5

    cvt_x_kernel<<<dim3(8192), dim3(256), 0, stream>>>(
        (const float4*)x, (int4*)xbf);

    prep_kernel<<<dim3(3072), dim3(256), 0, stream>>>(
        qkv_w, proj_w, btab, pidx, qkvw_bf, projw_bf, epb);

    // QKV: [262144,512]bf16 @ [1536,512]bf16^T -> bf16 (+bias, q*scale)
    // grid = 1024 m-tiles * 6 n-tiles
    gemm_bt<true><<<dim3(1024 * 6), dim3(512), 0, stream>>>(
        xbf, qkvw_bf, qkv_b, qkvbuf, 1536, 512, qscale);

    // fused window attention: 2048 windows x 16 heads
    attn_kernel<<<dim3(32768), dim3(256), 0, stream>>>(qkvbuf, epb, attnbuf);

    // proj: [262144,512]bf16 @ [512,512]bf16^T -> f32 (+bias)
    gemm_bt<false><<<dim3(1024 * 2), dim3(512), 0, stream>>>(
        attnbuf, projw_bf, proj_b, d_out, 512, 512, 1.0f);
}

// Round 4
// 1349.444 us; speedup vs baseline: 1.1472x; 1.1472x over previous
//
#include <hip/hip_runtime.h>
#include <hip/hip_bf16.h>

// EarthAttention2D on MI355X (gfx950).
// B_WIN=2048, N=128, DIM=512, HEADS=16, hd=32, M = 2048*128 = 262144.
// Pipeline: cvt_x (x->bf16) + prep (weights->bf16, epb gather)
//        -> QKV GEMM (128^2 tile, BK=32, 3-buf counted-vmcnt prefetch;
//           epilogue writes Q[b,h,n,d], K[b,h,n,d], Vt[b,h,d,n])
//        -> fused window attention (gload_lds Q/K, padded Vt)
//        -> proj GEMM (same template, f32 out).

typedef short short8 __attribute__((ext_vector_type(8)));
typedef float f32x4 __attribute__((ext_vector_type(4)));
typedef unsigned short u16;
typedef unsigned int u32;

__device__ __forceinline__ u16 f2bf(float f) {
    __bf16 h = (__bf16)f;                    // RNE fptrunc -> v_cvt on gfx950
    union { __bf16 b; u16 u; } v; v.b = h;
    return v.u;
}

__device__ __forceinline__ f32x4 mfma16(short8 a, short8 b, f32x4 c) {
    return __builtin_amdgcn_mfma_f32_16x16x32_bf16(a, b, c, 0, 0, 0);
}

// async global->LDS, 16B per lane, dest = wave-uniform base + lane*16
#define GLDS16(gsrc, ldst)                                                  \
    __builtin_amdgcn_global_load_lds(                                       \
        (const __attribute__((address_space(1))) void*)(gsrc),              \
        (__attribute__((address_space(3))) void*)(ldst), 16, 0, 0)

// ---------------------------------------------------------------- cvt_x ----
__global__ __launch_bounds__(256) void cvt_x_kernel(
    const float4* __restrict__ xin, int4* __restrict__ xbf)
{
    int idx = blockIdx.x * 256 + threadIdx.x;           // unit = 8 floats
    for (; idx < 16777216; idx += 8192 * 256) {
        const float4 a = xin[idx * 2], b = xin[idx * 2 + 1];
        int4 o;
        o.x = (u32)f2bf(a.x) | ((u32)f2bf(a.y) << 16);
        o.y = (u32)f2bf(a.z) | ((u32)f2bf(a.w) << 16);
        o.z = (u32)f2bf(b.x) | ((u32)f2bf(b.y) << 16);
        o.w = (u32)f2bf(b.z) | ((u32)f2bf(b.w) << 16);
        xbf[idx] = o;
    }
}

// ---------------------------------------------------------------- prep ----
__global__ __launch_bounds__(256) void prep_kernel(
    const float* __restrict__ qkv_w, const float* __restrict__ proj_w,
    const float* __restrict__ btab, const int* __restrict__ pidx,
    u16* __restrict__ qkvw_bf, u16* __restrict__ projw_bf,
    float* __restrict__ epb)
{
    const int i = blockIdx.x * 256 + threadIdx.x;    // grid = 3072*256 = 786432
    qkvw_bf[i] = f2bf(qkv_w[i]);
    if (i < 512 * 512) projw_bf[i] = f2bf(proj_w[i]);
    if (i < 16 * 128 * 128) {
        const int rc = i & 16383, h = i >> 14;
        epb[i] = btab[pidx[rc] * 128 + 64 + h];      // bias_table[idx][TOW/2=4][h]
    }
}

// ---------------------------------------------------------------- GEMM ----
// C[M,Nn] = A[M,K] @ Bt[Nn,K]^T (+bias).  128x128 tile, BK=32, 4 waves.
// LDS: 3 buffers x (A[128][32] + B[128][32]) = 48 KiB -> 3 blocks/CU.
// Fragment reads from [128][32] are 8-lane-broadcast, conflict-free (no
// swizzle needed).  Loop: STAGE(t+2) -> ds_read(t) -> MFMA -> vmcnt(4)
// [never 0 until tail] -> s_barrier.  One barrier per K-tile; prefetched
// loads stay in flight across barriers (T4).
//
// EPI_QKV: per-tile t_sel = bn>>2 (0=Q,1=K,2=V), 4 heads per tile.
//   Q/K: out[((b*16+h)*128 + n)*32 + d] = (acc+bias)*scale  (head-major)
//   V:   out[((b*16+h)*32 + d)*128 + n] = acc+bias          (transposed)
// else: f32 direct stores (+bias) to Cv.

template<bool EPI_QKV>
__global__ __launch_bounds__(256) void gemm_bt(
    const u16* __restrict__ A, const u16* __restrict__ Bt,
    const float* __restrict__ bias, void* __restrict__ Cv,
    u16* __restrict__ kb, u16* __restrict__ vtb,
    const int Nn, const int K, const float qscale)
{
    __shared__ __attribute__((aligned(16))) char sm[49152];

    const int tid = threadIdx.x;
    const int lane = tid & 63;
    const int w = tid >> 6;
    const int lo = lane & 15, g = lane >> 4;
    const int wm = w >> 1, wn = w & 1;
    const int wofs = __builtin_amdgcn_readfirstlane(w) * 1024;
    const int ntile = Nn >> 7;

    int wg = blockIdx.x;
    {   // bijective XCD swizzle (gridDim % 8 == 0 for all launches)
        const int cpx = gridDim.x >> 3;
        wg = (wg & 7) * cpx + (wg >> 3);
    }
    const int bm = wg / ntile, bn = wg % ntile;
    const size_t m0 = (size_t)bm << 7;
    const int n0 = bn << 7;
    const int nk = K >> 5;                               // 16

    // staging source pointers: slot = w*64+lane; r = slot>>2 (16 rows/wave),
    // c8 = (slot&3)*8 -> 4 lanes cover one 64B row segment.
    const int slot = w * 64 + lane;
    const int rs = slot >> 2, c8 = (slot & 3) * 8;
    const u16* pa0 = A + (m0 + rs) * (size_t)K + c8;
    const u16* pa1 = pa0 + (size_t)64 * K;
    const u16* pb0 = Bt + (size_t)(n0 + rs) * K + c8;
    const u16* pb1 = pb0 + (size_t)64 * K;

#define STAGE(buf, kt)                                                     \
    do {                                                                   \
        const int ko = (kt) << 5;                                          \
        char* d = sm + (buf) * 16384 + wofs;                               \
        GLDS16(pa0 + ko, d);                                               \
        GLDS16(pa1 + ko, d + 4096);                                        \
        GLDS16(pb0 + ko, d + 8192);                                        \
        GLDS16(pb1 + ko, d + 12288);                                       \
    } while (0)

    f32x4 acc[4][4] = {};

    STAGE(0, 0);
    STAGE(1, 1);
    asm volatile("s_waitcnt vmcnt(4)" ::: "memory");     // tile0 resident
    __builtin_amdgcn_s_barrier();

    int cur = 0, pre = 2;
    for (int t = 0; t < nk; ++t) {
        if (t + 2 < nk) STAGE(pre, t + 2);
        const char* Ab = sm + cur * 16384;
        const char* Bb = Ab + 8192;
        short8 af[4], bq[4];
#pragma unroll
        for (int i = 0; i < 4; ++i) {
            af[i] = *(const short8*)(Ab + (wm * 64 + i * 16 + lo) * 64 + g * 16);
            bq[i] = *(const short8*)(Bb + (wn * 64 + i * 16 + lo) * 64 + g * 16);
        }
#pragma unroll
        for (int i = 0; i < 4; ++i)
#pragma unroll
            for (int j = 0; j < 4; ++j)
                acc[i][j] = mfma16(af[i], bq[j], acc[i][j]);
        if (t + 2 < nk) asm volatile("s_waitcnt vmcnt(4)" ::: "memory");
        else            asm volatile("s_waitcnt vmcnt(0)" ::: "memory");
        asm volatile("" ::: "memory");
        __builtin_amdgcn_s_barrier();
        cur = (cur == 2) ? 0 : cur + 1;
        pre = (pre == 2) ? 0 : pre + 1;
    }
#undef STAGE

    if constexpr (EPI_QKV) {
        u16* Ct = (u16*)sm;                              // [128][136] max 34 KiB
        const int b16 = ((int)(m0 >> 7)) * 16;
        const int tsel = bn >> 2;                        // 0=q,1=k,2=v
        const int h0 = (bn & 3) << 2;
        u16* outb = (tsel == 0) ? (u16*)Cv : (tsel == 1) ? kb : vtb;
        if (tsel < 2) {
            const float sc = (tsel == 0) ? qscale : 1.0f;
#pragma unroll
            for (int j = 0; j < 4; ++j) {
                const int c = wn * 64 + j * 16 + lo;
                const float bv = bias[n0 + c];
#pragma unroll
                for (int i = 0; i < 4; ++i)
#pragma unroll
                    for (int ii = 0; ii < 4; ++ii) {
                        const int r = wm * 64 + i * 16 + g * 4 + ii;
                        Ct[r * 136 + c] = f2bf((acc[i][j][ii] + bv) * sc);
                    }
            }
            __syncthreads();
#pragma unroll
            for (int it = 0; it < 8; ++it) {
                const int idx = it * 256 + tid;
                const int r = idx >> 4, s2 = idx & 15;
                const int hl = s2 >> 2, d0 = (s2 & 3) * 8;
                *(int4*)(outb + ((size_t)(b16 + h0 + hl) * 128 + r) * 32 + d0) =
                    *(const int4*)(Ct + r * 136 + s2 * 8);
            }
        } else {
            // V: restage transposed -> global [b,h,d,n]
#pragma unroll
            for (int j = 0; j < 4; ++j) {
                const int c = wn * 64 + j * 16 + lo;
                const float bv = bias[n0 + c];
#pragma unroll
                for (int i = 0; i < 4; ++i)
#pragma unroll
                    for (int ii = 0; ii < 4; ++ii) {
                        const int r = wm * 64 + i * 16 + g * 4 + ii;
                        Ct[c * 136 + r] = f2bf(acc[i][j][ii] + bv);
                    }
            }
            __syncthreads();
#pragma unroll
            for (int it = 0; it < 8; ++it) {
                const int idx = it * 256 + tid;
                const int cidx = idx >> 4, nc = idx & 15;
                const int hl = cidx >> 5, d = cidx & 31;
                *(int4*)(outb + ((size_t)(b16 + h0 + hl) * 32 + d) * 128 + nc * 8) =
                    *(const int4*)(Ct + cidx * 136 + nc * 8);
            }
        }
    } else {
        float* Cg = (float*)Cv;
#pragma unroll
        for (int j = 0; j < 4; ++j) {
            const int c = wn * 64 + j * 16 + lo;
            const float bv = bias[n0 + c];
#pragma unroll
            for (int i = 0; i < 4; ++i)
#pragma unroll
                for (int ii = 0; ii < 4; ++ii) {
                    const size_t r = m0 + wm * 64 + i * 16 + g * 4 + ii;
                    Cg[r * (size_t)Nn + n0 + c] = acc[i][j][ii] + bv;
                }
        }
    }
}

// ----------------------------------------------------------- attention ----
// One block (4 waves) per (b, h).  Inputs head-major: Q[b,h,n,d], K[b,h,n,d],
// Vt[b,h,d,n] (pre-transposed by the QKV epilogue).  Q/K staged via
// global_load_lds (linear [128][32]: frag reads are 8-lane-broadcast, free);
// Vt reg-staged into padded [32][136].  Union LDS 43520 B -> 3 blocks/CU.
__global__ __launch_bounds__(256) void attn_kernel(
    const u16* __restrict__ qbuf, const u16* __restrict__ kbuf,
    const u16* __restrict__ vtbuf, const float* __restrict__ epb,
    u16* __restrict__ aout)
{
    __shared__ __attribute__((aligned(16))) char smem[43520];
    u16 (*Vt)[136]      = (u16(*)[136])smem;                 // [32][136]
    u16 (*Qs)[32]       = (u16(*)[32])(smem + 8704);         // [128][32]
    u16 (*Ks)[32]       = (u16(*)[32])(smem + 16896);        // [128][32]
    u16 (*Ps)[32][136]  = (u16(*)[32][136])(smem + 8704);    // [4][32][136]
    u16 (*Os)[32]       = (u16(*)[32])smem;                  // [128][32]

    const int h = blockIdx.x >> 11;
    const int b = blockIdx.x & 2047;
    const int tid = threadIdx.x;
    const int lane = tid & 63, w = tid >> 6;
    const int lo = lane & 15, g = lane >> 4;
    const int wu = __builtin_amdgcn_readfirstlane(w);

    const size_t hb = (size_t)(b * 16 + h) * 4096;
    const u16* qp = qbuf + hb;
    const u16* kp = kbuf + hb;
    const u16* vp = vtbuf + hb;

    // Q/K via global_load_lds: 8 chunks of 1024B each, wave w does 2w, 2w+1
#pragma unroll
    for (int cc = 0; cc < 2; ++cc) {
        const int ch = wu * 2 + cc;
        GLDS16(qp + ch * 512 + lane * 8, (char*)Qs + ch * 1024);
        GLDS16(kp + ch * 512 + lane * 8, (char*)Ks + ch * 1024);
    }
    // Vt: coalesced int4 loads -> padded LDS rows
#pragma unroll
    for (int it = 0; it < 2; ++it) {
        const int idx = tid + it * 256;          // 0..511
        const int d = idx >> 4, nc = idx & 15;
        const int4 v = *(const int4*)(vp + idx * 8);
        *(int4*)(&Vt[d][nc * 8]) = v;
    }
    __syncthreads();

    const int r0 = w * 32;

    // ---- S = Q @ K^T ----
    short8 aq[2], bk[8];
    aq[0] = *(const short8*)(&Qs[r0 + lo][g * 8]);
    aq[1] = *(const short8*)(&Qs[r0 + 16 + lo][g * 8]);
#pragma unroll
    for (int j = 0; j < 8; ++j) bk[j] = *(const short8*)(&Ks[j * 16 + lo][g * 8]);

    f32x4 acc[2][8];
#pragma unroll
    for (int j = 0; j < 8; ++j) {
        f32x4 z = {0.f, 0.f, 0.f, 0.f};
        acc[0][j] = mfma16(aq[0], bk[j], z);
        acc[1][j] = mfma16(aq[1], bk[j], z);
    }

    // ---- bias + row max ----
    const float* eb = epb + (h << 14);
    float mrow[2][4], rsum[2][4];
#pragma unroll
    for (int mt = 0; mt < 2; ++mt)
#pragma unroll
        for (int ii = 0; ii < 4; ++ii) { mrow[mt][ii] = -1e30f; rsum[mt][ii] = 0.f; }

#pragma unroll
    for (int mt = 0; mt < 2; ++mt)
#pragma unroll
        for (int j = 0; j < 8; ++j)
#pragma unroll
            for (int ii = 0; ii < 4; ++ii) {
                const int r = r0 + mt * 16 + g * 4 + ii;
                const int c = j * 16 + lo;
                const float sv = acc[mt][j][ii] + eb[(r << 7) + c];
                acc[mt][j][ii] = sv;
                mrow[mt][ii] = fmaxf(mrow[mt][ii], sv);
            }
#pragma unroll
    for (int d = 1; d < 16; d <<= 1)
#pragma unroll
        for (int mt = 0; mt < 2; ++mt)
#pragma unroll
            for (int ii = 0; ii < 4; ++ii)
                mrow[mt][ii] = fmaxf(mrow[mt][ii], __shfl_xor(mrow[mt][ii], d, 64));

    __syncthreads();   // all waves done reading Qs/Ks -> Ps may overwrite

    // ---- exp -> Ps (per-wave private region), row sums ----
#pragma unroll
    for (int mt = 0; mt < 2; ++mt)
#pragma unroll
        for (int j = 0; j < 8; ++j)
#pragma unroll
            for (int ii = 0; ii < 4; ++ii) {
                const float p = __expf(acc[mt][j][ii] - mrow[mt][ii]);
                rsum[mt][ii] += p;
                Ps[w][mt * 16 + g * 4 + ii][j * 16 + lo] = f2bf(p);
            }
#pragma unroll
    for (int d = 1; d < 16; d <<= 1)
#pragma unroll
        for (int mt = 0; mt < 2; ++mt)
#pragma unroll
            for (int ii = 0; ii < 4; ++ii)
                rsum[mt][ii] += __shfl_xor(rsum[mt][ii], d, 64);

    // ---- O = P @ V ----
    f32x4 o[2][2] = {};
#pragma unroll
    for (int kk = 0; kk < 4; ++kk) {
        short8 av[2];
        av[0] = *(const short8*)(&Ps[w][lo][kk * 32 + g * 8]);
        av[1] = *(const short8*)(&Ps[w][16 + lo][kk * 32 + g * 8]);
#pragma unroll
        for (int dt = 0; dt < 2; ++dt) {
            const short8 bv = *(const short8*)(&Vt[dt * 16 + lo][kk * 32 + g * 8]);
            o[0][dt] = mfma16(av[0], bv, o[0][dt]);
            o[1][dt] = mfma16(av[1], bv, o[1][dt]);
        }
    }

    __syncthreads();   // all waves done reading Vt -> Os may overwrite

    // ---- normalize -> Os, coalesced int4 stores ----
#pragma unroll
    for (int mt = 0; mt < 2; ++mt)
#pragma unroll
        for (int dt = 0; dt < 2; ++dt)
#pragma unroll
            for (int ii = 0; ii < 4; ++ii)
                Os[r0 + mt * 16 + g * 4 + ii][dt * 16 + lo] =
                    f2bf(o[mt][dt][ii] / rsum[mt][ii]);
    __syncthreads();

    u16* op = aout + (size_t)b * 128 * 512 + h * 32;
#pragma unroll
    for (int it = 0; it < 2; ++it) {
        const int idx = tid + it * 256;          // 0..511
        const int r = idx >> 2, c = (idx & 3) * 8;
        *(int4*)(op + (size_t)r * 512 + c) = *(const int4*)(&Os[r][c]);
    }
}

// -------------------------------------------------------------- launch ----
extern "C" void kernel_launch(void* const* d_in, const int* in_sizes, int n_in,
                              void* d_out, int out_size, void* d_ws, size_t ws_size,
                              hipStream_t stream)
{
    const float* x      = (const float*)d_in[0];
    const float* qkv_w  = (const float*)d_in[1];
    const float* qkv_b  = (const float*)d_in[2];
    const float* proj_w = (const float*)d_in[3];
    const float* proj_b = (const float*)d_in[4];
    const float* btab   = (const float*)d_in[5];
    const int*   pidx   = (const int*)d_in[6];

    // workspace layout (bytes), total 1,076,887,552
    // xbf aliases attnbuf: x_bf16 is dead before attn writes its output.
    char* ws = (char*)d_ws;
    u16*   xbf      = (u16*)(ws);                        // 268,435,456
    u16*   attnbuf  = (u16*)(ws);                        // (alias)
    u16*   qkvw_bf  = (u16*)(ws + 268435456);            //   1,572,864
    u16*   projw_bf = (u16*)(ws + 270008320);            //     524,288
    float* epb      = (float*)(ws + 270532608);          //   1,048,576
    u16*   qbuf     = (u16*)(ws + 271581184);            // 268,435,456
    u16*   kbuf     = (u16*)(ws + 540016640);            // 268,435,456
    u16*   vtbuf    = (u16*)(ws + 808452096);            // 268,435,456

    const float qscale = 0.17677669529663687f;           // 32^-0.5

    cvt_x_kernel<<<dim3(8192), dim3(256), 0, stream>>>(
        (const float4*)x, (int4*)xbf);

    prep_kernel<<<dim3(3072), dim3(256), 0, stream>>>(
        qkv_w, proj_w, btab, pidx, qkvw_bf, projw_bf, epb);

    // QKV: [262144,512]bf16 @ [1536,512]bf16^T -> Q/K/Vt head-major buffers
    gemm_bt<true><<<dim3(2048 * 12), dim3(256), 0, stream>>>(
        xbf, qkvw_bf, qkv_b, qbuf, kbuf, vtbuf, 1536, 512, qscale);

    // fused window attention: 2048 windows x 16 heads
    attn_kernel<<<dim3(32768), dim3(256), 0, stream>>>(
        qbuf, kbuf, vtbuf, epb, attnbuf);

    // proj: [262144,512]bf16 @ [512,512]bf16^T -> f32 (+bias)
    gemm_bt<false><<<dim3(2048 * 4), dim3(256), 0, stream>>>(
        attnbuf, projw_bf, proj_b, d_out, nullptr, nullptr, 512, 512, 1.0f);
}

// Round 5
// 1340.657 us; speedup vs baseline: 1.1547x; 1.0066x over previous
//
#include <hip/hip_runtime.h>
#include <hip/hip_bf16.h>

// EarthAttention2D on MI355X (gfx950).
// B_WIN=2048, N=128, DIM=512, HEADS=16, hd=32, M = 2048*128 = 262144.
// Pipeline: cvt_x (x->bf16) + prep (weights->bf16, epb gather)
//        -> QKV GEMM (128^2 tile, BK=32, 3-buf counted-vmcnt prefetch,
//           quarter-wave-swizzled LDS; epilogue writes Q/K[b,h,n,d], Vt[b,h,d,n])
//        -> fused window attention (gload_lds Q/K swizzled, padded Vt)
//        -> proj GEMM (same template, f32 out).
//
// LDS swizzle derivation (BK=32, 64B rows): ds_read_b128 quarter-wave
// (16 lanes, g fixed) must spread over all 8 128B-aligned 4-bank groups.
// group = (r&1)*4 + slot. With slot = g ^ ((r>>1)&3) and r = base16 + lo:
// (lo&1, (lo>>1)&3) enumerates all 8 groups twice -> 2 lanes/group = free
// (m136). Content: LDS slot s of row r holds global chunk s ^ ((r>>1)&3);
// GLDS dest stays linear, the global SOURCE address carries the inverse
// swizzle (m173).

typedef short short8 __attribute__((ext_vector_type(8)));
typedef float f32x4 __attribute__((ext_vector_type(4)));
typedef unsigned short u16;
typedef unsigned int u32;

__device__ __forceinline__ u16 f2bf(float f) {
    __bf16 h = (__bf16)f;                    // RNE fptrunc -> v_cvt on gfx950
    union { __bf16 b; u16 u; } v; v.b = h;
    return v.u;
}

__device__ __forceinline__ f32x4 mfma16(short8 a, short8 b, f32x4 c) {
    return __builtin_amdgcn_mfma_f32_16x16x32_bf16(a, b, c, 0, 0, 0);
}

// async global->LDS, 16B per lane, dest = wave-uniform base + lane*16
#define GLDS16(gsrc, ldst)                                                  \
    __builtin_amdgcn_global_load_lds(                                       \
        (const __attribute__((address_space(1))) void*)(gsrc),              \
        (__attribute__((address_space(3))) void*)(ldst), 16, 0, 0)

// ---------------------------------------------------------------- cvt_x ----
__global__ __launch_bounds__(256) void cvt_x_kernel(
    const float4* __restrict__ xin, int4* __restrict__ xbf)
{
    int idx = blockIdx.x * 256 + threadIdx.x;           // unit = 8 floats
    for (; idx < 16777216; idx += 8192 * 256) {
        const float4 a = xin[idx * 2], b = xin[idx * 2 + 1];
        int4 o;
        o.x = (u32)f2bf(a.x) | ((u32)f2bf(a.y) << 16);
        o.y = (u32)f2bf(a.z) | ((u32)f2bf(a.w) << 16);
        o.z = (u32)f2bf(b.x) | ((u32)f2bf(b.y) << 16);
        o.w = (u32)f2bf(b.z) | ((u32)f2bf(b.w) << 16);
        xbf[idx] = o;
    }
}

// ---------------------------------------------------------------- prep ----
__global__ __launch_bounds__(256) void prep_kernel(
    const float* __restrict__ qkv_w, const float* __restrict__ proj_w,
    const float* __restrict__ btab, const int* __restrict__ pidx,
    u16* __restrict__ qkvw_bf, u16* __restrict__ projw_bf,
    float* __restrict__ epb)
{
    const int i = blockIdx.x * 256 + threadIdx.x;    // grid = 3072*256 = 786432
    qkvw_bf[i] = f2bf(qkv_w[i]);
    if (i < 512 * 512) projw_bf[i] = f2bf(proj_w[i]);
    if (i < 16 * 128 * 128) {
        const int rc = i & 16383, h = i >> 14;
        epb[i] = btab[pidx[rc] * 128 + 64 + h];      // bias_table[idx][TOW/2=4][h]
    }
}

// ---------------------------------------------------------------- GEMM ----
// C[M,Nn] = A[M,K] @ Bt[Nn,K]^T (+bias).  128x128 tile, BK=32, 4 waves.
// LDS: 3 buffers x (A[128][32] + B[128][32]) = 48 KiB -> 3 blocks/CU.
// Loop: STAGE(t+2) -> ds_read(t) -> MFMA -> vmcnt(4) [never 0 until tail]
// -> s_barrier.  One barrier per K-tile; prefetched loads stay in flight
// across barriers (T4).  Quarter-wave swizzle per header comment.
//
// EPI_QKV: per-tile t_sel = bn>>2 (0=Q,1=K,2=V), 4 heads per tile.
//   Q/K: out[((b*16+h)*128 + n)*32 + d] = (acc+bias)*scale  (head-major)
//   V:   out[((b*16+h)*32 + d)*128 + n] = acc+bias          (transposed)
// else: f32 direct stores (+bias) to Cv.

template<bool EPI_QKV>
__global__ __launch_bounds__(256) void gemm_bt(
    const u16* __restrict__ A, const u16* __restrict__ Bt,
    const float* __restrict__ bias, void* __restrict__ Cv,
    u16* __restrict__ kb, u16* __restrict__ vtb,
    const int Nn, const int K, const float qscale)
{
    __shared__ __attribute__((aligned(16))) char sm[49152];

    const int tid = threadIdx.x;
    const int lane = tid & 63;
    const int w = tid >> 6;
    const int lo = lane & 15, g = lane >> 4;
    const int wm = w >> 1, wn = w & 1;
    const int wofs = __builtin_amdgcn_readfirstlane(w) * 1024;
    const int ntile = Nn >> 7;

    int wg = blockIdx.x;
    {   // bijective XCD swizzle (gridDim % 8 == 0 for all launches)
        const int cpx = gridDim.x >> 3;
        wg = (wg & 7) * cpx + (wg >> 3);
    }
    const int bm = wg / ntile, bn = wg % ntile;
    const size_t m0 = (size_t)bm << 7;
    const int n0 = bn << 7;
    const int nk = K >> 5;                               // 16

    // staging: slot = w*64+lane; row rs = slot>>2 (16 rows/wave), LDS slot
    // s = lane&3; source chunk = s ^ ((rs>>1)&3) = (lane&3) ^ ((lane>>3)&3).
    const int rs = w * 16 + (lane >> 2);
    const int c8 = (((lane & 3) ^ ((lane >> 3) & 3))) * 8;
    const u16* pa0 = A + (m0 + rs) * (size_t)K + c8;
    const u16* pa1 = pa0 + (size_t)64 * K;
    const u16* pb0 = Bt + (size_t)(n0 + rs) * K + c8;
    const u16* pb1 = pb0 + (size_t)64 * K;

#define STAGE(buf, kt)                                                     \
    do {                                                                   \
        const int ko = (kt) << 5;                                          \
        char* d = sm + (buf) * 16384 + wofs;                               \
        GLDS16(pa0 + ko, d);                                               \
        GLDS16(pa1 + ko, d + 4096);                                        \
        GLDS16(pb0 + ko, d + 8192);                                        \
        GLDS16(pb1 + ko, d + 12288);                                       \
    } while (0)

    f32x4 acc[4][4] = {};

    STAGE(0, 0);
    STAGE(1, 1);
    asm volatile("s_waitcnt vmcnt(4)" ::: "memory");     // tile0 resident
    __builtin_amdgcn_s_barrier();

    // ds_read col swizzle: chunk = g ^ ((lo>>1)&3)  (constant per lane)
    const int csw16 = (g ^ ((lo >> 1) & 3)) << 4;

    int cur = 0, pre = 2;
    for (int t = 0; t < nk; ++t) {
        if (t + 2 < nk) STAGE(pre, t + 2);
        const char* Ab = sm + cur * 16384;
        const char* Bb = Ab + 8192;
        short8 af[4], bq[4];
#pragma unroll
        for (int i = 0; i < 4; ++i) {
            af[i] = *(const short8*)(Ab + (wm * 64 + i * 16 + lo) * 64 + csw16);
            bq[i] = *(const short8*)(Bb + (wn * 64 + i * 16 + lo) * 64 + csw16);
        }
#pragma unroll
        for (int i = 0; i < 4; ++i)
#pragma unroll
            for (int j = 0; j < 4; ++j)
                acc[i][j] = mfma16(af[i], bq[j], acc[i][j]);
        if (t + 2 < nk) asm volatile("s_waitcnt vmcnt(4)" ::: "memory");
        else            asm volatile("s_waitcnt vmcnt(0)" ::: "memory");
        asm volatile("" ::: "memory");
        __builtin_amdgcn_s_barrier();
        cur = (cur == 2) ? 0 : cur + 1;
        pre = (pre == 2) ? 0 : pre + 1;
    }
#undef STAGE

    if constexpr (EPI_QKV) {
        u16* Ct = (u16*)sm;                              // [128][136] max 34 KiB
        const int b16 = ((int)(m0 >> 7)) * 16;
        const int tsel = bn >> 2;                        // 0=q,1=k,2=v
        const int h0 = (bn & 3) << 2;
        u16* outb = (tsel == 0) ? (u16*)Cv : (tsel == 1) ? kb : vtb;
        if (tsel < 2) {
            const float sc = (tsel == 0) ? qscale : 1.0f;
#pragma unroll
            for (int j = 0; j < 4; ++j) {
                const int c = wn * 64 + j * 16 + lo;
                const float bv = bias[n0 + c];
#pragma unroll
                for (int i = 0; i < 4; ++i)
#pragma unroll
                    for (int ii = 0; ii < 4; ++ii) {
                        const int r = wm * 64 + i * 16 + g * 4 + ii;
                        Ct[r * 136 + c] = f2bf((acc[i][j][ii] + bv) * sc);
                    }
            }
            __syncthreads();
#pragma unroll
            for (int it = 0; it < 8; ++it) {
                const int idx = it * 256 + tid;
                const int r = idx >> 4, s2 = idx & 15;
                const int hl = s2 >> 2, d0 = (s2 & 3) * 8;
                *(int4*)(outb + ((size_t)(b16 + h0 + hl) * 128 + r) * 32 + d0) =
                    *(const int4*)(Ct + r * 136 + s2 * 8);
            }
        } else {
            // V: restage transposed -> global [b,h,d,n]
#pragma unroll
            for (int j = 0; j < 4; ++j) {
                const int c = wn * 64 + j * 16 + lo;
                const float bv = bias[n0 + c];
#pragma unroll
                for (int i = 0; i < 4; ++i)
#pragma unroll
                    for (int ii = 0; ii < 4; ++ii) {
                        const int r = wm * 64 + i * 16 + g * 4 + ii;
                        Ct[c * 136 + r] = f2bf(acc[i][j][ii] + bv);
                    }
            }
            __syncthreads();
#pragma unroll
            for (int it = 0; it < 8; ++it) {
                const int idx = it * 256 + tid;
                const int cidx = idx >> 4, nc = idx & 15;
                const int hl = cidx >> 5, d = cidx & 31;
                *(int4*)(outb + ((size_t)(b16 + h0 + hl) * 32 + d) * 128 + nc * 8) =
                    *(const int4*)(Ct + cidx * 136 + nc * 8);
            }
        }
    } else {
        float* Cg = (float*)Cv;
#pragma unroll
        for (int j = 0; j < 4; ++j) {
            const int c = wn * 64 + j * 16 + lo;
            const float bv = bias[n0 + c];
#pragma unroll
            for (int i = 0; i < 4; ++i)
#pragma unroll
                for (int ii = 0; ii < 4; ++ii) {
                    const size_t r = m0 + wm * 64 + i * 16 + g * 4 + ii;
                    Cg[r * (size_t)Nn + n0 + c] = acc[i][j][ii] + bv;
                }
        }
    }
}

// ----------------------------------------------------------- attention ----
// One block (4 waves) per (b, h).  Inputs head-major: Q[b,h,n,d], K[b,h,n,d],
// Vt[b,h,d,n].  Q/K staged via global_load_lds with the same quarter-wave
// swizzle as the GEMM (64B rows); Vt reg-staged into padded [32][136].
// Union LDS 43520 B -> 3 blocks/CU.
__global__ __launch_bounds__(256) void attn_kernel(
    const u16* __restrict__ qbuf, const u16* __restrict__ kbuf,
    const u16* __restrict__ vtbuf, const float* __restrict__ epb,
    u16* __restrict__ aout)
{
    __shared__ __attribute__((aligned(16))) char smem[43520];
    u16 (*Vt)[136]      = (u16(*)[136])smem;                 // [32][136]
    char* Qs            = smem + 8704;                       // [128][32] swz
    char* Ks            = smem + 16896;                      // [128][32] swz
    u16 (*Ps)[32][136]  = (u16(*)[32][136])(smem + 8704);    // [4][32][136]
    u16 (*Os)[32]       = (u16(*)[32])smem;                  // [128][32]

    const int h = blockIdx.x >> 11;
    const int b = blockIdx.x & 2047;
    const int tid = threadIdx.x;
    const int lane = tid & 63, w = tid >> 6;
    const int lo = lane & 15, g = lane >> 4;
    const int wu = __builtin_amdgcn_readfirstlane(w);

    const size_t hb = (size_t)(b * 16 + h) * 4096;
    const u16* qp = qbuf + hb;
    const u16* kp = kbuf + hb;
    const u16* vp = vtbuf + hb;

    // Q/K via global_load_lds with inverse-swizzled source:
    // chunk within 8 chunks of 1024B; row = ch*16 + lane>>2, slot = lane&3,
    // source chunk = slot ^ ((row>>1)&3) = (lane&3) ^ ((lane>>3)&3).
    const int c8 = ((lane & 3) ^ ((lane >> 3) & 3)) * 8;
    const int rofs = (lane >> 2) * 32;
#pragma unroll
    for (int cc = 0; cc < 2; ++cc) {
        const int ch = wu * 2 + cc;
        GLDS16(qp + ch * 512 + rofs + c8, Qs + ch * 1024);
        GLDS16(kp + ch * 512 + rofs + c8, Ks + ch * 1024);
    }
    // Vt: coalesced int4 loads -> padded LDS rows
#pragma unroll
    for (int it = 0; it < 2; ++it) {
        const int idx = tid + it * 256;          // 0..511
        const int d = idx >> 4, nc = idx & 15;
        const int4 v = *(const int4*)(vp + idx * 8);
        *(int4*)(&Vt[d][nc * 8]) = v;
    }
    __syncthreads();

    const int r0 = w * 32;
    const int csw16 = (g ^ ((lo >> 1) & 3)) << 4;   // ds_read col swizzle

    // ---- S = Q @ K^T ----
    short8 aq[2], bk[8];
    aq[0] = *(const short8*)(Qs + (r0 + lo) * 64 + csw16);
    aq[1] = *(const short8*)(Qs + (r0 + 16 + lo) * 64 + csw16);
#pragma unroll
    for (int j = 0; j < 8; ++j)
        bk[j] = *(const short8*)(Ks + (j * 16 + lo) * 64 + csw16);

    f32x4 acc[2][8];
#pragma unroll
    for (int j = 0; j < 8; ++j) {
        f32x4 z = {0.f, 0.f, 0.f, 0.f};
        acc[0][j] = mfma16(aq[0], bk[j], z);
        acc[1][j] = mfma16(aq[1], bk[j], z);
    }

    // ---- bias + row max ----
    const float* eb = epb + (h << 14);
    float mrow[2][4], rsum[2][4];
#pragma unroll
    for (int mt = 0; mt < 2; ++mt)
#pragma unroll
        for (int ii = 0; ii < 4; ++ii) { mrow[mt][ii] = -1e30f; rsum[mt][ii] = 0.f; }

#pragma unroll
    for (int mt = 0; mt < 2; ++mt)
#pragma unroll
        for (int j = 0; j < 8; ++j)
#pragma unroll
            for (int ii = 0; ii < 4; ++ii) {
                const int r = r0 + mt * 16 + g * 4 + ii;
                const int c = j * 16 + lo;
                const float sv = acc[mt][j][ii] + eb[(r << 7) + c];
                acc[mt][j][ii] = sv;
                mrow[mt][ii] = fmaxf(mrow[mt][ii], sv);
            }
#pragma unroll
    for (int d = 1; d < 16; d <<= 1)
#pragma unroll
        for (int mt = 0; mt < 2; ++mt)
#pragma unroll
            for (int ii = 0; ii < 4; ++ii)
                mrow[mt][ii] = fmaxf(mrow[mt][ii], __shfl_xor(mrow[mt][ii], d, 64));

    __syncthreads();   // all waves done reading Qs/Ks -> Ps may overwrite

    // ---- exp -> Ps (per-wave private region), row sums ----
#pragma unroll
    for (int mt = 0; mt < 2; ++mt)
#pragma unroll
        for (int j = 0; j < 8; ++j)
#pragma unroll
            for (int ii = 0; ii < 4; ++ii) {
                const float p = __expf(acc[mt][j][ii] - mrow[mt][ii]);
                rsum[mt][ii] += p;
                Ps[w][mt * 16 + g * 4 + ii][j * 16 + lo] = f2bf(p);
            }
#pragma unroll
    for (int d = 1; d < 16; d <<= 1)
#pragma unroll
        for (int mt = 0; mt < 2; ++mt)
#pragma unroll
            for (int ii = 0; ii < 4; ++ii)
                rsum[mt][ii] += __shfl_xor(rsum[mt][ii], d, 64);

    // ---- O = P @ V ----
    f32x4 o[2][2] = {};
#pragma unroll
    for (int kk = 0; kk < 4; ++kk) {
        short8 av[2];
        av[0] = *(const short8*)(&Ps[w][lo][kk * 32 + g * 8]);
        av[1] = *(const short8*)(&Ps[w][16 + lo][kk * 32 + g * 8]);
#pragma unroll
        for (int dt = 0; dt < 2; ++dt) {
            const short8 bv = *(const short8*)(&Vt[dt * 16 + lo][kk * 32 + g * 8]);
            o[0][dt] = mfma16(av[0], bv, o[0][dt]);
            o[1][dt] = mfma16(av[1], bv, o[1][dt]);
        }
    }

    __syncthreads();   // all waves done reading Vt -> Os may overwrite

    // ---- normalize -> Os, coalesced int4 stores ----
#pragma unroll
    for (int mt = 0; mt < 2; ++mt)
#pragma unroll
        for (int dt = 0; dt < 2; ++dt)
#pragma unroll
            for (int ii = 0; ii < 4; ++ii)
                Os[r0 + mt * 16 + g * 4 + ii][dt * 16 + lo] =
                    f2bf(o[mt][dt][ii] / rsum[mt][ii]);
    __syncthreads();

    u16* op = aout + (size_t)b * 128 * 512 + h * 32;
#pragma unroll
    for (int it = 0; it < 2; ++it) {
        const int idx = tid + it * 256;          // 0..511
        const int r = idx >> 2, c = (idx & 3) * 8;
        *(int4*)(op + (size_t)r * 512 + c) = *(const int4*)(&Os[r][c]);
    }
}

// -------------------------------------------------------------- launch ----
extern "C" void kernel_launch(void* const* d_in, const int* in_sizes, int n_in,
                              void* d_out, int out_size, void* d_ws, size_t ws_size,
                              hipStream_t stream)
{
    const float* x      = (const float*)d_in[0];
    const float* qkv_w  = (const float*)d_in[1];
    const float* qkv_b  = (const float*)d_in[2];
    const float* proj_w = (const float*)d_in[3];
    const float* proj_b = (const float*)d_in[4];
    const float* btab   = (const float*)d_in[5];
    const int*   pidx   = (const int*)d_in[6];

    // workspace layout (bytes), total 1,076,887,552
    // xbf aliases attnbuf: x_bf16 is dead before attn writes its output.
    char* ws = (char*)d_ws;
    u16*   xbf      = (u16*)(ws);                        // 268,435,456
    u16*   attnbuf  = (u16*)(ws);                        // (alias)
    u16*   qkvw_bf  = (u16*)(ws + 268435456);            //   1,572,864
    u16*   projw_bf = (u16*)(ws + 270008320);            //     524,288
    float* epb      = (float*)(ws + 270532608);          //   1,048,576
    u16*   qbuf     = (u16*)(ws + 271581184);            // 268,435,456
    u16*   kbuf     = (u16*)(ws + 540016640);            // 268,435,456
    u16*   vtbuf    = (u16*)(ws + 808452096);            // 268,435,456

    const float qscale = 0.17677669529663687f;           // 32^-0.5

    cvt_x_kernel<<<dim3(8192), dim3(256), 0, stream>>>(
        (const float4*)x, (int4*)xbf);

    prep_kernel<<<dim3(3072), dim3(256), 0, stream>>>(
        qkv_w, proj_w, btab, pidx, qkvw_bf, projw_bf, epb);

    // QKV: [262144,512]bf16 @ [1536,512]bf16^T -> Q/K/Vt head-major buffers
    gemm_bt<true><<<dim3(2048 * 12), dim3(256), 0, stream>>>(
        xbf, qkvw_bf, qkv_b, qbuf, kbuf, vtbuf, 1536, 512, qscale);

    // fused window attention: 2048 windows x 16 heads
    attn_kernel<<<dim3(32768), dim3(256), 0, stream>>>(
        qbuf, kbuf, vtbuf, epb, attnbuf);

    // proj: [262144,512]bf16 @ [512,512]bf16^T -> f32 (+bias)
    gemm_bt<false><<<dim3(2048 * 4), dim3(256), 0, stream>>>(
        attnbuf, projw_bf, proj_b, d_out, nullptr, nullptr, 512, 512, 1.0f);
}